// Round 1
// baseline (69.808 us; speedup 1.0000x reference)
//
#include <hip/hip_runtime.h>
#include <math.h>

// Problem constants (fixed shapes from setup_inputs; mask_feat_stride = 8,
// MASK_OUT_STRIDE = 4 -> upsample factor = 2).
#define H_IN   136
#define W_IN   200
#define STRIDE 8
#define OH     (H_IN * 2)   // 272
#define OW     (W_IN * 2)   // 400
#define RB     17           // low-res rows per strip (136 = 8*17)
#define NSTRIP 8
#define LROWS  (RB + 1)     // +1 halo row above
#define CH     8
#define CIN    8
#define NPARAM 169

// Param layout per instance (169 floats):
//  [0..79]    w0 [8][10]
//  [80..143]  w1 [8][8]
//  [144..151] w2 [8]
//  [152..159] b0 [8]
//  [160..167] b1 [8]
//  [168]      b2

__global__ __launch_bounds__(256) void mask_head_fused(
    const float* __restrict__ mask_feats,   // (N, 8, H, W)
    const float* __restrict__ params,       // (n_inst, 169)
    const float* __restrict__ locations,    // (n_inst, 2)
    const int*   __restrict__ im_inds,      // (n_inst,)
    const int*   __restrict__ fpn_levels,   // (n_inst,)
    const float* __restrict__ soi_tab,      // (5,)
    float* __restrict__ out)                // (n_inst, OH, OW)
{
    __shared__ float Llds[LROWS * W_IN];    // low-res logits tile (18*200*4 = 14.4 KB)

    const int inst  = blockIdx.x >> 3;      // / NSTRIP
    const int strip = blockIdx.x & 7;
    const int r0    = strip * RB;
    const int tid   = threadIdx.x;

    // Uniform (blockIdx-derived) per-instance scalars -> scalar loads.
    const float* P = params + inst * NPARAM;
    const float loc_x  = locations[2 * inst];
    const float loc_y  = locations[2 * inst + 1];
    const float inv_soi = 1.0f / soi_tab[fpn_levels[inst]];
    const int   im      = im_inds[inst];
    const float* F = mask_feats + (size_t)im * (CIN * H_IN * W_IN);

    // ---- Phase 1: low-res logits for rows r0-1 .. r0+RB-1 (clamped) into LDS ----
    for (int idx = tid; idx < LROWS * W_IN; idx += 256) {
        int k = idx / W_IN;
        int c = idx - k * W_IN;
        int r = r0 - 1 + k;
        r = max(0, min(r, H_IN - 1));

        float xin[CIN + 2];
        xin[0] = (loc_x - (float)(c * STRIDE + STRIDE / 2)) * inv_soi;
        xin[1] = (loc_y - (float)(r * STRIDE + STRIDE / 2)) * inv_soi;
        #pragma unroll
        for (int ch = 0; ch < CIN; ++ch)
            xin[2 + ch] = F[ch * (H_IN * W_IN) + r * W_IN + c];

        float h0[CH];
        #pragma unroll
        for (int o = 0; o < CH; ++o) {
            float a = P[152 + o];
            #pragma unroll
            for (int i = 0; i < CIN + 2; ++i)
                a = fmaf(P[o * (CIN + 2) + i], xin[i], a);
            h0[o] = fmaxf(a, 0.0f);
        }
        float h1[CH];
        #pragma unroll
        for (int o = 0; o < CH; ++o) {
            float a = P[160 + o];
            #pragma unroll
            for (int i = 0; i < CH; ++i)
                a = fmaf(P[80 + o * CH + i], h0[i], a);
            h1[o] = fmaxf(a, 0.0f);
        }
        float lg = P[168];
        #pragma unroll
        for (int i = 0; i < CH; ++i)
            lg = fmaf(P[144 + i], h1[i], lg);

        Llds[idx] = lg;
    }
    __syncthreads();

    // ---- Phase 2: aligned-bilinear 2x upsample + sigmoid ----
    // out[y,x] = R[max(y-1,0), max(x-1,0)], R = align_corners resize of the
    // edge-padded (H+1, W+1) tile: i0 = j>>1, frac = (j&1)*0.5, rows/cols
    // clamped to H-1 / W-1.
    float* O = out + (size_t)inst * (OH * OW);
    for (int idx = tid; idx < 2 * RB * OW; idx += 256) {
        int yl = idx / OW;
        int x  = idx - yl * OW;
        int y  = 2 * r0 + yl;

        int   jy = max(y - 1, 0);
        int   a0 = jy >> 1;
        float fy = (jy & 1) ? 0.5f : 0.0f;
        int   k0 = min(a0, H_IN - 1) - r0 + 1;
        int   k1 = min(a0 + 1, H_IN - 1) - r0 + 1;
        k0 = min(k0, LROWS - 1);
        k1 = min(k1, LROWS - 1);   // only ever clamps when fy == 0

        int   jx = max(x - 1, 0);
        int   b0 = jx >> 1;
        float fx = (jx & 1) ? 0.5f : 0.0f;
        int   c0 = min(b0, W_IN - 1);
        int   c1 = min(b0 + 1, W_IN - 1);

        float v00 = Llds[k0 * W_IN + c0];
        float v01 = Llds[k0 * W_IN + c1];
        float v10 = Llds[k1 * W_IN + c0];
        float v11 = Llds[k1 * W_IN + c1];

        float top = fmaf(fx, v01 - v00, v00);
        float bot = fmaf(fx, v11 - v10, v10);
        float lg  = fmaf(fy, bot - top, top);

        O[y * OW + x] = 1.0f / (1.0f + __expf(-lg));
    }
}

extern "C" void kernel_launch(void* const* d_in, const int* in_sizes, int n_in,
                              void* d_out, int out_size, void* d_ws, size_t ws_size,
                              hipStream_t stream) {
    const float* mask_feats = (const float*)d_in[0];
    const float* params     = (const float*)d_in[1];
    const float* locations  = (const float*)d_in[2];
    const int*   im_inds    = (const int*)d_in[3];
    const int*   fpn_levels = (const int*)d_in[4];
    const float* soi_tab    = (const float*)d_in[5];
    // d_in[6] = mask_feat_stride (device scalar, == 8 for this problem;
    // upsample factor 8/4 = 2 is baked into the kernel).

    const int n_inst = in_sizes[1] / NPARAM;   // 128
    dim3 grid(n_inst * NSTRIP);
    mask_head_fused<<<grid, 256, 0, stream>>>(
        mask_feats, params, locations, im_inds, fpn_levels, soi_tab, (float*)d_out);
}

// Round 2
// 50.915 us; speedup vs baseline: 1.3711x; 1.3711x over previous
//
#include <hip/hip_runtime.h>
#include <math.h>

typedef float f32x2 __attribute__((ext_vector_type(2)));

#define H_IN   136
#define W_IN   200
#define OH     272
#define OW     400
#define RB     8            // low-res rows produced per strip (17 strips * 8 = 136)
#define NSTRIP 17
#define LROWS  (RB + 1)     // +1 halo row above
#define CH     8
#define CIN    8
#define NPARAM 169
#define HW     (H_IN * W_IN)

// Param layout per instance (169 floats):
//  [0..79] w0[8][10] | [80..143] w1[8][8] | [144..151] w2[8]
//  [152..159] b0[8]  | [160..167] b1[8]   | [168] b2

__device__ __forceinline__ float sigmoidf_fast(float v) {
    return __builtin_amdgcn_rcpf(1.0f + __expf(-v));
}

__global__ __launch_bounds__(256) void mask_head_fused(
    const float* __restrict__ mask_feats,   // (N, 8, H, W)
    const float* __restrict__ params,       // (n_inst, 169)
    const float* __restrict__ locations,    // (n_inst, 2)
    const int*   __restrict__ im_inds,      // (n_inst,)
    const int*   __restrict__ fpn_levels,   // (n_inst,)
    const float* __restrict__ soi_tab,      // (5,)
    float* __restrict__ out)                // (n_inst, OH, OW)
{
    __shared__ float Llds[LROWS][W_IN];     // 9*200*4 = 7.2 KB

    const int inst  = blockIdx.x / NSTRIP;
    const int strip = blockIdx.x - inst * NSTRIP;
    const int r0    = strip * RB;
    const int tid   = threadIdx.x;

    // blockIdx-uniform per-instance scalars -> SGPR-resident
    const float* P = params + inst * NPARAM;
    const float loc_x   = locations[2 * inst];
    const float loc_y   = locations[2 * inst + 1];
    const float inv_soi = 1.0f / soi_tab[fpn_levels[inst]];
    const float* F = mask_feats + (size_t)im_inds[inst] * (CIN * HW);

    // ---- Phase 1: low-res logits, 2 adjacent pixels per thread (packed fp32) ----
    for (int idx = tid; idx < LROWS * (W_IN / 2); idx += 256) {   // 900 items
        int k  = idx / (W_IN / 2);
        int c2 = idx - k * (W_IN / 2);
        int c  = 2 * c2;
        int r  = min(max(r0 - 1 + k, 0), H_IN - 1);

        f32x2 xin[CIN + 2];
        float rx0 = (loc_x - (float)(c * 8 + 4)) * inv_soi;
        xin[0] = (f32x2){rx0, rx0 - 8.0f * inv_soi};
        float ry  = (loc_y - (float)(r * 8 + 4)) * inv_soi;
        xin[1] = (f32x2){ry, ry};
        const float* Fp = F + r * W_IN + c;
        #pragma unroll
        for (int ch = 0; ch < CIN; ++ch)
            xin[2 + ch] = *(const f32x2*)(Fp + ch * HW);

        const f32x2 zero2 = {0.0f, 0.0f};
        f32x2 h0[CH];
        #pragma unroll
        for (int o = 0; o < CH; ++o) {
            float b = P[152 + o];
            f32x2 a = {b, b};
            #pragma unroll
            for (int i = 0; i < CIN + 2; ++i) {
                float w = P[o * (CIN + 2) + i];
                a = __builtin_elementwise_fma((f32x2){w, w}, xin[i], a);
            }
            h0[o] = __builtin_elementwise_max(a, zero2);
        }
        f32x2 h1[CH];
        #pragma unroll
        for (int o = 0; o < CH; ++o) {
            float b = P[160 + o];
            f32x2 a = {b, b};
            #pragma unroll
            for (int i = 0; i < CH; ++i) {
                float w = P[80 + o * CH + i];
                a = __builtin_elementwise_fma((f32x2){w, w}, h0[i], a);
            }
            h1[o] = __builtin_elementwise_max(a, zero2);
        }
        float b2 = P[168];
        f32x2 lg = {b2, b2};
        #pragma unroll
        for (int i = 0; i < CH; ++i) {
            float w = P[144 + i];
            lg = __builtin_elementwise_fma((f32x2){w, w}, h1[i], lg);
        }
        *(f32x2*)&Llds[k][c] = lg;
    }
    __syncthreads();

    // ---- Phase 2: 2x aligned-bilinear upsample + sigmoid, float4 per thread ----
    // out[y,x] = R[max(y-1,0), max(x-1,0)], i0=j>>1, frac=(j&1)*0.5, clamped.
    // 4 consecutive x (x0=4t) need LDS cols {x0/2-1, x0/2, x0/2+1}:
    //   o0 = 0.5(A+B), o1 = B, o2 = 0.5(B+C), o3 = C   (after row-lerp)
    float* O = out + (size_t)inst * (OH * OW);
    for (int idx = tid; idx < 2 * RB * (OW / 4); idx += 256) {    // 1600 items
        int yl = idx / (OW / 4);
        int t  = idx - yl * (OW / 4);
        int x0 = 4 * t;
        int y  = 2 * r0 + yl;

        int   jy  = max(y - 1, 0);
        int   a0i = jy >> 1;
        float fy  = (jy & 1) ? 0.5f : 0.0f;
        int k0 = min(min(a0i,     H_IN - 1) - r0 + 1, LROWS - 1);
        int k1 = min(min(a0i + 1, H_IN - 1) - r0 + 1, LROWS - 1);

        int ca = max(x0 / 2 - 1, 0);
        int cb = x0 / 2;
        int cc = x0 / 2 + 1;          // <= 199

        float A = fmaf(fy, Llds[k1][ca] - Llds[k0][ca], Llds[k0][ca]);
        float B = fmaf(fy, Llds[k1][cb] - Llds[k0][cb], Llds[k0][cb]);
        float C = fmaf(fy, Llds[k1][cc] - Llds[k0][cc], Llds[k0][cc]);

        float4 res;
        res.x = sigmoidf_fast(0.5f * (A + B));
        res.y = sigmoidf_fast(B);
        res.z = sigmoidf_fast(0.5f * (B + C));
        res.w = sigmoidf_fast(C);
        *(float4*)(O + y * OW + x0) = res;
    }
}

extern "C" void kernel_launch(void* const* d_in, const int* in_sizes, int n_in,
                              void* d_out, int out_size, void* d_ws, size_t ws_size,
                              hipStream_t stream) {
    const float* mask_feats = (const float*)d_in[0];
    const float* params     = (const float*)d_in[1];
    const float* locations  = (const float*)d_in[2];
    const int*   im_inds    = (const int*)d_in[3];
    const int*   fpn_levels = (const int*)d_in[4];
    const float* soi_tab    = (const float*)d_in[5];
    // d_in[6] = mask_feat_stride (== 8 here; factor 2 upsample baked in)

    const int n_inst = in_sizes[1] / NPARAM;   // 128
    dim3 grid(n_inst * NSTRIP);
    mask_head_fused<<<grid, 256, 0, stream>>>(
        mask_feats, params, locations, im_inds, fpn_levels, soi_tab, (float*)d_out);
}

// Round 3
// 40.827 us; speedup vs baseline: 1.7098x; 1.2471x over previous
//
#include <hip/hip_runtime.h>
#include <math.h>

#define H_IN   136
#define W_IN   200
#define OH     272
#define OW     400
#define RB     8            // low-res rows produced per strip (17 strips * 8 = 136)
#define NSTRIP 17
#define LROWS  (RB + 1)     // +1 halo row above
#define CH     8
#define CIN    8
#define NPARAM 169
#define HW     (H_IN * W_IN)
#define NEG_LOG2E (-1.4426950408889634f)

// Param layout per instance (169 floats):
//  [0..79] w0[8][10] | [80..143] w1[8][8] | [144..151] w2[8]
//  [152..159] b0[8]  | [160..167] b1[8]   | [168] b2

__global__ __launch_bounds__(256, 4) void mask_head_fused(
    const float* __restrict__ mask_feats,   // (N, 8, H, W)
    const float* __restrict__ params,       // (n_inst, 169)
    const float* __restrict__ locations,    // (n_inst, 2)
    const int*   __restrict__ im_inds,      // (n_inst,)
    const int*   __restrict__ fpn_levels,   // (n_inst,)
    const float* __restrict__ soi_tab,      // (5,)
    float* __restrict__ out)                // (n_inst, OH, OW)
{
    __shared__ float Llds[LROWS][W_IN];     // holds t = -log2e * logit

    const int inst  = blockIdx.x / NSTRIP;
    const int strip = blockIdx.x - inst * NSTRIP;
    const int r0    = strip * RB;
    const int tid   = threadIdx.x;

    // blockIdx-uniform per-instance scalars -> SGPR-resident
    const float* P = params + inst * NPARAM;
    const float loc_x   = locations[2 * inst];
    const float loc_y   = locations[2 * inst + 1];
    const float inv_soi = 1.0f / soi_tab[fpn_levels[inst]];
    const float* F = mask_feats + (size_t)im_inds[inst] * (CIN * HW);

    // ---- Phase 1: low-res scaled logits, 4 adjacent pixels per thread, scalar fp32 ----
    // Codegen goal: every FMA is v_fma_f32 v_acc, s_weight, v_x, v_acc (1 inst/FMA).
    for (int idx = tid; idx < LROWS * (W_IN / 4); idx += 256) {   // 450 items
        int k  = idx / (W_IN / 4);
        int c4 = idx - k * (W_IN / 4);
        int c  = 4 * c4;
        int r  = min(max(r0 - 1 + k, 0), H_IN - 1);

        // features: 8 channels x 4 px
        const float* Fp = F + r * W_IN + c;
        float4 f[CIN];
        #pragma unroll
        for (int ch = 0; ch < CIN; ++ch)
            f[ch] = *(const float4*)(Fp + ch * HW);

        float rx0 = (loc_x - (float)(c * 8 + 4)) * inv_soi;
        float dx  = -8.0f * inv_soi;
        float rx[4] = {rx0, rx0 + dx, rx0 + 2.0f * dx, rx0 + 3.0f * dx};
        float ry  = (loc_y - (float)(r * 8 + 4)) * inv_soi;

        float h0[CH][4];
        #pragma unroll
        for (int o = 0; o < CH; ++o) {
            float b = P[152 + o];
            float wx = P[o * 10 + 0];
            float wy = P[o * 10 + 1];
            float a0 = b, a1 = b, a2 = b, a3 = b;
            a0 = fmaf(wx, rx[0], a0); a1 = fmaf(wx, rx[1], a1);
            a2 = fmaf(wx, rx[2], a2); a3 = fmaf(wx, rx[3], a3);
            a0 = fmaf(wy, ry, a0); a1 = fmaf(wy, ry, a1);
            a2 = fmaf(wy, ry, a2); a3 = fmaf(wy, ry, a3);
            #pragma unroll
            for (int i = 0; i < CIN; ++i) {
                float w = P[o * 10 + 2 + i];
                a0 = fmaf(w, f[i].x, a0); a1 = fmaf(w, f[i].y, a1);
                a2 = fmaf(w, f[i].z, a2); a3 = fmaf(w, f[i].w, a3);
            }
            h0[o][0] = fmaxf(a0, 0.0f); h0[o][1] = fmaxf(a1, 0.0f);
            h0[o][2] = fmaxf(a2, 0.0f); h0[o][3] = fmaxf(a3, 0.0f);
        }

        float h1[CH][4];
        #pragma unroll
        for (int o = 0; o < CH; ++o) {
            float b = P[160 + o];
            float a0 = b, a1 = b, a2 = b, a3 = b;
            #pragma unroll
            for (int i = 0; i < CH; ++i) {
                float w = P[80 + o * CH + i];
                a0 = fmaf(w, h0[i][0], a0); a1 = fmaf(w, h0[i][1], a1);
                a2 = fmaf(w, h0[i][2], a2); a3 = fmaf(w, h0[i][3], a3);
            }
            h1[o][0] = fmaxf(a0, 0.0f); h1[o][1] = fmaxf(a1, 0.0f);
            h1[o][2] = fmaxf(a2, 0.0f); h1[o][3] = fmaxf(a3, 0.0f);
        }

        // layer 2, pre-scaled by -log2(e) so phase 2 uses exp2 directly
        float b2 = NEG_LOG2E * P[168];
        float t0 = b2, t1 = b2, t2 = b2, t3 = b2;
        #pragma unroll
        for (int i = 0; i < CH; ++i) {
            float w = NEG_LOG2E * P[144 + i];
            t0 = fmaf(w, h1[i][0], t0); t1 = fmaf(w, h1[i][1], t1);
            t2 = fmaf(w, h1[i][2], t2); t3 = fmaf(w, h1[i][3], t3);
        }
        *(float4*)&Llds[k][c] = make_float4(t0, t1, t2, t3);
    }
    __syncthreads();

    // ---- Phase 2: 2x aligned-bilinear upsample + sigmoid, 8 px/thread ----
    // out[y,x] = R[max(y-1,0), max(x-1,0)], i0=j>>1, frac=(j&1)*0.5, clamped.
    // 8 consecutive x (x0=8t) need row-lerped cols {4t-1, 4t, 4t+1, 4t+2, 4t+3}.
    float* O = out + (size_t)inst * (OH * OW);
    for (int idx = tid; idx < 2 * RB * (OW / 8); idx += 256) {    // 800 items
        int yl = idx / (OW / 8);
        int t  = idx - yl * (OW / 8);
        int y  = 2 * r0 + yl;

        int   jy  = max(y - 1, 0);
        int   a0i = jy >> 1;
        float fy  = (jy & 1) ? 0.5f : 0.0f;
        int k0 = min(min(a0i,     H_IN - 1) - r0 + 1, LROWS - 1);
        int k1 = min(min(a0i + 1, H_IN - 1) - r0 + 1, LROWS - 1);

        int cm = 4 * t;
        int cp = max(cm - 4, 0);
        float4 m0 = *(const float4*)&Llds[k0][cm];
        float4 m1 = *(const float4*)&Llds[k1][cm];
        float4 p0 = *(const float4*)&Llds[k0][cp];
        float4 p1 = *(const float4*)&Llds[k1][cp];

        // row lerp (t-space)
        float B = fmaf(fy, m1.x - m0.x, m0.x);
        float C = fmaf(fy, m1.y - m0.y, m0.y);
        float D = fmaf(fy, m1.z - m0.z, m0.z);
        float E = fmaf(fy, m1.w - m0.w, m0.w);
        float A = (t == 0) ? B : fmaf(fy, p1.w - p0.w, p0.w);

        float v[8];
        v[0] = 0.5f * (A + B); v[1] = B;
        v[2] = 0.5f * (B + C); v[3] = C;
        v[4] = 0.5f * (C + D); v[5] = D;
        v[6] = 0.5f * (D + E); v[7] = E;

        float4 r0v, r1v;
        r0v.x = __builtin_amdgcn_rcpf(1.0f + __builtin_amdgcn_exp2f(v[0]));
        r0v.y = __builtin_amdgcn_rcpf(1.0f + __builtin_amdgcn_exp2f(v[1]));
        r0v.z = __builtin_amdgcn_rcpf(1.0f + __builtin_amdgcn_exp2f(v[2]));
        r0v.w = __builtin_amdgcn_rcpf(1.0f + __builtin_amdgcn_exp2f(v[3]));
        r1v.x = __builtin_amdgcn_rcpf(1.0f + __builtin_amdgcn_exp2f(v[4]));
        r1v.y = __builtin_amdgcn_rcpf(1.0f + __builtin_amdgcn_exp2f(v[5]));
        r1v.z = __builtin_amdgcn_rcpf(1.0f + __builtin_amdgcn_exp2f(v[6]));
        r1v.w = __builtin_amdgcn_rcpf(1.0f + __builtin_amdgcn_exp2f(v[7]));

        float* Op = O + y * OW + 8 * t;
        *(float4*)(Op)     = r0v;
        *(float4*)(Op + 4) = r1v;
    }
}

extern "C" void kernel_launch(void* const* d_in, const int* in_sizes, int n_in,
                              void* d_out, int out_size, void* d_ws, size_t ws_size,
                              hipStream_t stream) {
    const float* mask_feats = (const float*)d_in[0];
    const float* params     = (const float*)d_in[1];
    const float* locations  = (const float*)d_in[2];
    const int*   im_inds    = (const int*)d_in[3];
    const int*   fpn_levels = (const int*)d_in[4];
    const float* soi_tab    = (const float*)d_in[5];
    // d_in[6] = mask_feat_stride (== 8 here; factor-2 upsample baked in)

    const int n_inst = in_sizes[1] / NPARAM;   // 128
    dim3 grid(n_inst * NSTRIP);
    mask_head_fused<<<grid, 256, 0, stream>>>(
        mask_feats, params, locations, im_inds, fpn_levels, soi_tab, (float*)d_out);
}